// Round 1
// baseline (106.208 us; speedup 1.0000x reference)
//
#include <hip/hip_runtime.h>
#include <math.h>

// ModelParallelCrossEntropy: loss = mean_b [ log(sum_v exp(x[b,v])) - x[b,label[b]] ]
// computed as online (max, sum-exp) in ONE streaming pass over the 524 MB logits.

#define VOCAB 128000
#define BATCH 1024
#define TPB 256

__global__ __launch_bounds__(TPB) void ce_row_kernel(const float* __restrict__ logits,
                                                     const int* __restrict__ labels,
                                                     float* __restrict__ row_loss) {
    const int row = blockIdx.x;
    const float4* __restrict__ rp =
        reinterpret_cast<const float4*>(logits + (size_t)row * VOCAB);
    const int n4 = VOCAB / 4;  // 32000, exactly 125 iters per thread

    float m = -INFINITY;
    float s = 0.0f;

    for (int i = threadIdx.x; i < n4; i += TPB) {
        float4 v = rp[i];
        float m4 = fmaxf(fmaxf(v.x, v.y), fmaxf(v.z, v.w));
        if (m4 > m) {           // rarely taken after warm-up on random data
            s *= __expf(m - m4);
            m = m4;
        }
        s += __expf(v.x - m) + __expf(v.y - m) + __expf(v.z - m) + __expf(v.w - m);
    }

    // 64-lane wave reduction of (m, s)
    #pragma unroll
    for (int off = 1; off < 64; off <<= 1) {
        float mo = __shfl_down(m, off);
        float so = __shfl_down(s, off);
        float mn = fmaxf(m, mo);
        s = s * __expf(m - mn) + so * __expf(mo - mn);
        m = mn;
    }

    __shared__ float sm[TPB / 64], ss[TPB / 64];
    const int wave = threadIdx.x >> 6;
    const int lane = threadIdx.x & 63;
    if (lane == 0) { sm[wave] = m; ss[wave] = s; }
    __syncthreads();

    if (threadIdx.x == 0) {
        float M = sm[0], S = ss[0];
        #pragma unroll
        for (int w = 1; w < TPB / 64; ++w) {
            float mn = fmaxf(M, sm[w]);
            S = S * __expf(M - mn) + ss[w] * __expf(sm[w] - mn);
            M = mn;
        }
        const float xl = logits[(size_t)row * VOCAB + labels[row]];
        row_loss[row] = (M - xl) + __logf(S);
    }
}

__global__ __launch_bounds__(TPB) void ce_reduce_kernel(const float* __restrict__ row_loss,
                                                        float* __restrict__ out) {
    float v = 0.0f;
    for (int i = threadIdx.x; i < BATCH; i += TPB) v += row_loss[i];
    #pragma unroll
    for (int off = 1; off < 64; off <<= 1) v += __shfl_down(v, off);

    __shared__ float sv[TPB / 64];
    if ((threadIdx.x & 63) == 0) sv[threadIdx.x >> 6] = v;
    __syncthreads();
    if (threadIdx.x == 0) {
        float t = 0.0f;
        #pragma unroll
        for (int w = 0; w < TPB / 64; ++w) t += sv[w];
        out[0] = t / (float)BATCH;
    }
}

extern "C" void kernel_launch(void* const* d_in, const int* in_sizes, int n_in,
                              void* d_out, int out_size, void* d_ws, size_t ws_size,
                              hipStream_t stream) {
    const float* logits = (const float*)d_in[0];
    const int* labels = (const int*)d_in[1];
    float* row_loss = (float*)d_ws;   // 1024 floats = 4 KB scratch
    float* out = (float*)d_out;

    ce_row_kernel<<<BATCH, TPB, 0, stream>>>(logits, labels, row_loss);
    ce_reduce_kernel<<<1, TPB, 0, stream>>>(row_loss, out);
}

// Round 2
// 98.140 us; speedup vs baseline: 1.0822x; 1.0822x over previous
//
#include <hip/hip_runtime.h>
#include <math.h>

// ModelParallelCrossEntropy: loss = mean_b [ log(sum_v exp(x[b,v])) - x[b,label[b]] ]
// One streaming pass over the 524 MB logits, split 5 ways per row for max occupancy.

#define VOCAB 128000
#define BATCH 1024
#define SPLITS 5                 // 5 blocks per row
#define TPB 256
#define CHUNK4 (VOCAB / 4 / SPLITS)   // 6400 float4 per block; 25 per thread, exact

__global__ __launch_bounds__(TPB) void ce_partial_kernel(const float* __restrict__ logits,
                                                         float* __restrict__ part_m,
                                                         float* __restrict__ part_s) {
    const int blk = blockIdx.x;
    const int row = blk / SPLITS;
    const int split = blk % SPLITS;
    const float4* __restrict__ rp =
        reinterpret_cast<const float4*>(logits + (size_t)row * VOCAB) + split * CHUNK4;

    float m = -INFINITY;
    float s = 0.0f;

    // 25 exact iterations, branchless body -> compiler unrolls & pipelines loads.
    #pragma unroll 5
    for (int i = threadIdx.x; i < CHUNK4; i += TPB) {
        float4 v = rp[i];
        float m4 = fmaxf(fmaxf(v.x, v.y), fmaxf(v.z, v.w));
        float mn = fmaxf(m, m4);
        s = s * __expf(m - mn)
            + __expf(v.x - mn) + __expf(v.y - mn)
            + __expf(v.z - mn) + __expf(v.w - mn);
        m = mn;
    }

    // 64-lane wave reduction of (m, s)
    #pragma unroll
    for (int off = 1; off < 64; off <<= 1) {
        float mo = __shfl_down(m, off);
        float so = __shfl_down(s, off);
        float mn = fmaxf(m, mo);
        s = s * __expf(m - mn) + so * __expf(mo - mn);
        m = mn;
    }

    __shared__ float sm[TPB / 64], ss[TPB / 64];
    const int wave = threadIdx.x >> 6;
    if ((threadIdx.x & 63) == 0) { sm[wave] = m; ss[wave] = s; }
    __syncthreads();

    if (threadIdx.x == 0) {
        float M = sm[0], S = ss[0];
        #pragma unroll
        for (int w = 1; w < TPB / 64; ++w) {
            float mn = fmaxf(M, sm[w]);
            S = S * __expf(M - mn) + ss[w] * __expf(sm[w] - mn);
            M = mn;
        }
        part_m[blk] = M;
        part_s[blk] = S;
    }
}

__global__ __launch_bounds__(TPB) void ce_combine_kernel(const float* __restrict__ part_m,
                                                         const float* __restrict__ part_s,
                                                         const float* __restrict__ logits,
                                                         const int* __restrict__ labels,
                                                         float* __restrict__ out) {
    float local = 0.0f;
    for (int r = threadIdx.x; r < BATCH; r += TPB) {
        float M = part_m[r * SPLITS];
        float S = part_s[r * SPLITS];
        #pragma unroll
        for (int k = 1; k < SPLITS; ++k) {
            float pm = part_m[r * SPLITS + k];
            float ps = part_s[r * SPLITS + k];
            float mn = fmaxf(M, pm);
            S = S * __expf(M - mn) + ps * __expf(pm - mn);
            M = mn;
        }
        float xl = logits[(size_t)r * VOCAB + labels[r]];
        local += (M - xl) + __logf(S);
    }

    #pragma unroll
    for (int off = 1; off < 64; off <<= 1) local += __shfl_down(local, off);

    __shared__ float sv[TPB / 64];
    if ((threadIdx.x & 63) == 0) sv[threadIdx.x >> 6] = local;
    __syncthreads();
    if (threadIdx.x == 0) {
        float t = 0.0f;
        #pragma unroll
        for (int w = 0; w < TPB / 64; ++w) t += sv[w];
        out[0] = t / (float)BATCH;
    }
}

extern "C" void kernel_launch(void* const* d_in, const int* in_sizes, int n_in,
                              void* d_out, int out_size, void* d_ws, size_t ws_size,
                              hipStream_t stream) {
    const float* logits = (const float*)d_in[0];
    const int* labels = (const int*)d_in[1];
    float* part_m = (float*)d_ws;                       // 5120 floats
    float* part_s = (float*)d_ws + BATCH * SPLITS;      // 5120 floats
    float* out = (float*)d_out;

    ce_partial_kernel<<<BATCH * SPLITS, TPB, 0, stream>>>(logits, part_m, part_s);
    ce_combine_kernel<<<1, TPB, 0, stream>>>(part_m, part_s, logits, labels, out);
}

// Round 3
// 86.534 us; speedup vs baseline: 1.2274x; 1.1341x over previous
//
#include <hip/hip_runtime.h>
#include <math.h>

// ModelParallelCrossEntropy: loss = mean_b [ log(sum_v exp(x[b,v])) - x[b,label[b]] ]
// One streaming pass; each row split into 25 chunks, each thread owns exactly
// 20 floats (5x float4 nontemporal loads) -> max + exp-sum entirely in registers.

#define VOCAB 128000
#define BATCH 1024
#define SPLITS 25
#define TPB 256
#define CHUNK (VOCAB / SPLITS)        // 5120 floats per block
#define CHUNK4 (CHUNK / 4)            // 1280 float4 per block (5 per thread)

typedef float f32x4 __attribute__((ext_vector_type(4)));

__global__ __launch_bounds__(TPB) void ce_partial_kernel(const float* __restrict__ logits,
                                                         const int* __restrict__ labels,
                                                         float* __restrict__ part_m,
                                                         float* __restrict__ part_s,
                                                         float* __restrict__ row_xl) {
    const int blk = blockIdx.x;
    const int row = blk / SPLITS;
    const int split = blk % SPLITS;
    const float* rowp = logits + (size_t)row * VOCAB;
    const f32x4* __restrict__ rp =
        reinterpret_cast<const f32x4*>(rowp + split * CHUNK);

    // 5 independent streaming loads, issued together.
    const int t = threadIdx.x;
    f32x4 v0 = __builtin_nontemporal_load(rp + t);
    f32x4 v1 = __builtin_nontemporal_load(rp + t + TPB);
    f32x4 v2 = __builtin_nontemporal_load(rp + t + 2 * TPB);
    f32x4 v3 = __builtin_nontemporal_load(rp + t + 3 * TPB);
    f32x4 v4 = __builtin_nontemporal_load(rp + t + 4 * TPB);

    // max of the 20 values (tree)
    float m0 = fmaxf(fmaxf(v0[0], v0[1]), fmaxf(v0[2], v0[3]));
    float m1 = fmaxf(fmaxf(v1[0], v1[1]), fmaxf(v1[2], v1[3]));
    float m2 = fmaxf(fmaxf(v2[0], v2[1]), fmaxf(v2[2], v2[3]));
    float m3 = fmaxf(fmaxf(v3[0], v3[1]), fmaxf(v3[2], v3[3]));
    float m4 = fmaxf(fmaxf(v4[0], v4[1]), fmaxf(v4[2], v4[3]));
    float m = fmaxf(fmaxf(fmaxf(m0, m1), fmaxf(m2, m3)), m4);

    // exp-sum of 20 values against the thread max
    float s0 = __expf(v0[0] - m) + __expf(v0[1] - m) + __expf(v0[2] - m) + __expf(v0[3] - m);
    float s1 = __expf(v1[0] - m) + __expf(v1[1] - m) + __expf(v1[2] - m) + __expf(v1[3] - m);
    float s2 = __expf(v2[0] - m) + __expf(v2[1] - m) + __expf(v2[2] - m) + __expf(v2[3] - m);
    float s3 = __expf(v3[0] - m) + __expf(v3[1] - m) + __expf(v3[2] - m) + __expf(v3[3] - m);
    float s4 = __expf(v4[0] - m) + __expf(v4[1] - m) + __expf(v4[2] - m) + __expf(v4[3] - m);
    float s = ((s0 + s1) + (s2 + s3)) + s4;

    // 64-lane butterfly reduction of (m, s)
    #pragma unroll
    for (int off = 1; off < 64; off <<= 1) {
        float mo = __shfl_xor(m, off);
        float so = __shfl_xor(s, off);
        float mn = fmaxf(m, mo);
        s = s * __expf(m - mn) + so * __expf(mo - mn);
        m = mn;
    }

    __shared__ float sm[TPB / 64], ss[TPB / 64];
    const int wave = threadIdx.x >> 6;
    if ((threadIdx.x & 63) == 0) { sm[wave] = m; ss[wave] = s; }
    __syncthreads();

    if (threadIdx.x == 0) {
        float M = sm[0], S = ss[0];
        #pragma unroll
        for (int w = 1; w < TPB / 64; ++w) {
            float mn = fmaxf(M, sm[w]);
            S = S * __expf(M - mn) + ss[w] * __expf(sm[w] - mn);
            M = mn;
        }
        part_m[blk] = M;
        part_s[blk] = S;

        // label gather: exactly one chunk per row owns the label
        int lab = labels[row];
        int lo = split * CHUNK;
        if (lab >= lo && lab < lo + CHUNK) row_xl[row] = rowp[lab];
    }
}

#define CTPB 1024
__global__ __launch_bounds__(CTPB) void ce_combine_kernel(const float* __restrict__ part_m,
                                                          const float* __restrict__ part_s,
                                                          const float* __restrict__ row_xl,
                                                          float* __restrict__ out) {
    const int r = threadIdx.x;           // one row per thread
    float M = part_m[r * SPLITS];
    float S = part_s[r * SPLITS];
    #pragma unroll
    for (int k = 1; k < SPLITS; ++k) {
        float pm = part_m[r * SPLITS + k];
        float ps = part_s[r * SPLITS + k];
        float mn = fmaxf(M, pm);
        S = S * __expf(M - mn) + ps * __expf(pm - mn);
        M = mn;
    }
    float loss = (M - row_xl[r]) + __logf(S);

    #pragma unroll
    for (int off = 1; off < 64; off <<= 1) loss += __shfl_xor(loss, off);

    __shared__ float sv[CTPB / 64];
    if ((threadIdx.x & 63) == 0) sv[threadIdx.x >> 6] = loss;
    __syncthreads();
    if (threadIdx.x == 0) {
        float t = 0.0f;
        #pragma unroll
        for (int w = 0; w < CTPB / 64; ++w) t += sv[w];
        out[0] = t / (float)BATCH;
    }
}

extern "C" void kernel_launch(void* const* d_in, const int* in_sizes, int n_in,
                              void* d_out, int out_size, void* d_ws, size_t ws_size,
                              hipStream_t stream) {
    const float* logits = (const float*)d_in[0];
    const int* labels = (const int*)d_in[1];
    float* part_m = (float*)d_ws;                            // 25600 floats
    float* part_s = part_m + BATCH * SPLITS;                 // 25600 floats
    float* row_xl = part_s + BATCH * SPLITS;                 // 1024 floats
    float* out = (float*)d_out;

    ce_partial_kernel<<<BATCH * SPLITS, TPB, 0, stream>>>(logits, labels,
                                                          part_m, part_s, row_xl);
    ce_combine_kernel<<<1, CTPB, 0, stream>>>(part_m, part_s, row_xl, out);
}